// Round 12
// baseline (127.232 us; speedup 1.0000x reference)
//
#include <hip/hip_runtime.h>
#include <hip/hip_bf16.h>

typedef __attribute__((ext_vector_type(8))) short  short8;
typedef __attribute__((ext_vector_type(8))) unsigned short ushort8;
typedef __attribute__((ext_vector_type(4))) unsigned short usv4;
typedef __attribute__((ext_vector_type(4))) float  f32x4;

#define D_DIM 1152
#define O_DIM 256
#define N_TOT 100352
#define XT_H 58
#define XT_ROW (58 * 128)

__device__ __forceinline__ unsigned short f2bf(float f) {
  __hip_bfloat16 h = __float2bfloat16(f);
  return __builtin_bit_cast(unsigned short, h);
}

#define GLOAD_LDS16(g, l)                                              \
  __builtin_amdgcn_global_load_lds(                                    \
      (const __attribute__((address_space(1))) void*)(g),              \
      (__attribute__((address_space(3))) void*)(l), 16, 0, 0)

// ---------------------------------------------------------------------------
// Kernel 1: Wt[o][dn] via LDS-tiled fp32 block-GEMM (proven R4)
// ---------------------------------------------------------------------------
__global__ __launch_bounds__(256) void wt_kernel(
    const float* __restrict__ S1s, const float* __restrict__ U1s,
    const float* __restrict__ U2s, const float* __restrict__ S2s,
    unsigned short* __restrict__ Wt) {
  __shared__ float A_lds[32][64];
  __shared__ float B_lds[32][64];

  const int bo = blockIdx.x & 3;
  const int bd = blockIdx.x >> 2;
  const int o0  = bo << 6;
  const int dn0 = bd << 6;
  const int rr  = dn0 >> 7;
  const int c0  = dn0 & 127;

  const int tid = threadIdx.x;
  const int ty = tid >> 4, tx = tid & 15;

  float acc[4][4] = {};

  for (int kc = 0; kc < 15; ++kc) {
#pragma unroll
    for (int e = 0; e < 8; ++e) {
      const int li = e * 256 + tid;
      const int kk = li >> 6;
      const int xx = li & 63;
      const int k  = kc * 32 + kk;
      float av, bv;
      if (k < 48) {
        av = U1s[k * O_DIM + o0 + xx];
        const int d_old = (c0 + xx) * 9 + rr;
        bv = S1s[(size_t)((k >> 3) * D_DIM + d_old) * 8 + (k & 7)];
      } else {
        const int kq = k - 48;
        av = S2s[(size_t)kq * O_DIM + o0 + xx];
        const int d_old = (c0 + xx) * 9 + rr;
        bv = U2s[(size_t)kq * D_DIM + d_old];
      }
      A_lds[kk][xx] = av;
      B_lds[kk][xx] = bv;
    }
    __syncthreads();
#pragma unroll
    for (int kk = 0; kk < 32; ++kk) {
      f32x4 a = *(const f32x4*)&A_lds[kk][ty << 2];
      f32x4 b = *(const f32x4*)&B_lds[kk][tx << 2];
#pragma unroll
      for (int i = 0; i < 4; ++i)
#pragma unroll
        for (int j = 0; j < 4; ++j)
          acc[i][j] += a[i] * b[j];
    }
    __syncthreads();
  }

#pragma unroll
  for (int i = 0; i < 4; ++i) {
    usv4 v;
#pragma unroll
    for (int j = 0; j < 4; ++j) v[j] = f2bf(acc[i][j] * (1.0f / 6.0f));
    *(usv4*)(Wt + (size_t)(o0 + (ty << 2) + i) * D_DIM + dn0 + (tx << 2)) = v;
  }
}

// ---------------------------------------------------------------------------
// Kernel 2: pad+transpose x[B,C,H,W] fp32 -> x_t[b][ih][iw][c] bf16 (proven R4)
// ---------------------------------------------------------------------------
__global__ __launch_bounds__(256) void pad_kernel(const float* __restrict__ x,
                                                  unsigned short* __restrict__ xt) {
  int blk = blockIdx.x;
  int b = blk / XT_H, ih = blk - b * XT_H;
  unsigned short* dst = xt + (size_t)blk * XT_ROW;
  int tid = threadIdx.x;

  if (ih == 0 || ih == XT_H - 1) {
    ushort8 z;
#pragma unroll
    for (int q = 0; q < 8; ++q) z[q] = 0;
    for (int i = tid; i < XT_ROW / 8; i += 256) ((ushort8*)dst)[i] = z;
    return;
  }

  __shared__ unsigned short lds[128 * 58];
  int h = ih - 1;
  const float* xb = x + (size_t)b * 128 * 3136 + (size_t)h * 56;
#pragma unroll 4
  for (int r = 0; r < 28; ++r) {
    int idx = r * 256 + tid;
    int c = idx / 56, w2 = idx - c * 56;
    lds[c * 58 + w2] = f2bf(xb[(size_t)c * 3136 + w2]);
  }
  __syncthreads();
#pragma unroll 4
  for (int r = 0; r < 29; ++r) {
    int idx = r * 256 + tid;
    int iw = idx >> 7, c = idx & 127;
    unsigned short v = 0;
    if (iw >= 1 && iw <= 56) v = lds[c * 58 + (iw - 1)];
    dst[idx] = v;
  }
}

// ---------------------------------------------------------------------------
// Kernel 3: implicit-im2col GEMM, m201-faithful 4-phase/K-tile schedule.
// BM=256(o) x BN=256(n), BK=64, 8 waves (2Mx4N), wave-tile 128x64, acc[8][4].
// LDS: 2 bufs x [A 256x64 | B 256x64] bf16 = 2 x 64KB = 128KB. 128B rows,
// R7/R11-verified zero-conflict swizzle (granule ^= row&7, both sides).
// Per K-tile kt (buf = kt&1, staging -> buf^1 = kt+1's buffer, no race):
//  P1: ds_read A q0 ks0 (4) + B ks0 (4); stage B(kt+1) (4 gloads);
//      bar; lgkm0; setprio 16 MFMA; bar.
//  P2: ds_read A q1 ks0 (4);            stage A(kt+1) (4 gloads); ... 16 MFMA
//  P3: ds_read A q0 ks1 (4) + B ks1 (4);                          ... 16 MFMA
//  P4: ds_read A q1 ks1 (4); bar; lgkm0; 16 MFMA; vmcnt(0) [last stage was
//      P2 -> ~700cyc slack, drain costs ~0]; bar.
// Lag audit: every staged half is >=3 phases old at first read; ds_reads of a
// buffer complete (lgkm0) before the barrier preceding any overwrite of it.
// ---------------------------------------------------------------------------
__device__ __forceinline__ constexpr int KOF(int kt) {
  int rr = kt >> 1;
  return ((rr / 3) * 58 + (rr % 3)) * 128 + (kt & 1) * 64;
}

// staging: 4 gloads per operand per K-tile; gload r covers rows r*64..r*64+63
#define ST_A(kt_, bf_) do {                                                    \
  GLOAD_LDS16(pA[0] + (kt_) * 64, smem + (bf_) * 32768 + (0 * 64 + srow) * 64 + sgd); \
  GLOAD_LDS16(pA[1] + (kt_) * 64, smem + (bf_) * 32768 + (1 * 64 + srow) * 64 + sgd); \
  GLOAD_LDS16(pA[2] + (kt_) * 64, smem + (bf_) * 32768 + (2 * 64 + srow) * 64 + sgd); \
  GLOAD_LDS16(pA[3] + (kt_) * 64, smem + (bf_) * 32768 + (3 * 64 + srow) * 64 + sgd); \
} while (0)
#define ST_B(kt_, bf_) do {                                                    \
  GLOAD_LDS16(pB[0] + KOF(kt_), smem + (bf_) * 32768 + 16384 + (0 * 64 + srow) * 64 + sgd); \
  GLOAD_LDS16(pB[1] + KOF(kt_), smem + (bf_) * 32768 + 16384 + (1 * 64 + srow) * 64 + sgd); \
  GLOAD_LDS16(pB[2] + KOF(kt_), smem + (bf_) * 32768 + 16384 + (2 * 64 + srow) * 64 + sgd); \
  GLOAD_LDS16(pB[3] + KOF(kt_), smem + (bf_) * 32768 + 16384 + (3 * 64 + srow) * 64 + sgd); \
} while (0)

// fragment reads: 128B rows; granule = (ks*4 + (lane>>4)) ^ (row&7)
#define AFRAG(bf_, row_, ks_)                                                  \
  (*(const short8*)((const char*)smem + (bf_) * 65536 + (row_) * 128 +        \
      (((((ks_) << 2) + (lane >> 4)) ^ ((row_) & 7)) << 4)))
#define BFRAG(bf_, row_, ks_)                                                  \
  (*(const short8*)((const char*)smem + (bf_) * 65536 + 32768 + (row_) * 128 +\
      (((((ks_) << 2) + (lane >> 4)) ^ ((row_) & 7)) << 4)))

#define MFMA_Q(qbase, ksel) do {                                               \
  __builtin_amdgcn_s_setprio(1);                                               \
  _Pragma("unroll")                                                            \
  for (int mi = 0; mi < 4; ++mi)                                               \
    _Pragma("unroll")                                                          \
    for (int ni = 0; ni < 4; ++ni)                                             \
      acc[(qbase) + mi][ni] = __builtin_amdgcn_mfma_f32_16x16x32_bf16(         \
          afr[mi], bfr[ni], acc[(qbase) + mi][ni], 0, 0, 0);                   \
  __builtin_amdgcn_s_setprio(0);                                               \
} while (0)

__global__ __launch_bounds__(512, 1) void gemm_kernel(
    const unsigned short* __restrict__ Wt, const unsigned short* __restrict__ xt,
    const float* __restrict__ bias, float* __restrict__ out) {
  __shared__ __align__(1024) unsigned short smem[65536];  // 128 KiB

  // XCD swizzle (392 % 8 == 0): each XCD gets 49 consecutive n-tiles.
  const int bid   = blockIdx.x;
  const int ntile = (bid & 7) * 49 + (bid >> 3);
  const int n0    = ntile << 8;

  const int tid  = threadIdx.x;
  const int lane = tid & 63;
  const int w    = tid >> 6;
  const int wm   = w >> 2;       // 0..1 (o half: 128 rows)
  const int wn   = w & 3;        // 0..3 (n quarter: 64 rows)
  const int la15 = lane & 15;

  // staging geometry: gload covers 512thr x 16B = 8KB = 64 rows x 128B.
  const int srow = tid >> 3;                 // 0..63
  const int sg   = (tid & 7) ^ (srow & 7);   // pre-swizzled source granule
  const int sgd  = (tid & 7) << 3;           // linear LDS granule (elems)

  const unsigned short* pA[4];
  const unsigned short* pB[4];
#pragma unroll
  for (int r = 0; r < 4; ++r) {
    pA[r] = Wt + (size_t)(r * 64 + srow) * D_DIM + sg * 8;
    const int n_g = n0 + r * 64 + srow;
    const int b   = n_g / 3136;
    const int s   = n_g - b * 3136;
    const int oh  = s / 56, ow = s - oh * 56;
    pB[r] = xt + (((size_t)b * XT_H + oh) * XT_H + ow) * 128 + sg * 8;
  }

  f32x4 acc[8][4] = {};
  short8 afr[4], bfr[4];

  // ---- prologue: stage K-tile 0 into buf 0, full drain once ----
  ST_B(0, 0);
  ST_A(0, 0);
  asm volatile("s_waitcnt vmcnt(0)" ::: "memory");
  __builtin_amdgcn_s_barrier();

#pragma unroll
  for (int kt = 0; kt < 18; ++kt) {
    const int bf = kt & 1;
    const int nb = bf ^ 1;
    const bool more = (kt + 1) < 18;

    // ---- P1: A q0 ks0 + B ks0; stage B(kt+1) ----
#pragma unroll
    for (int mi = 0; mi < 4; ++mi)
      afr[mi] = AFRAG(bf, (wm << 7) + (mi << 4) + la15, 0);
#pragma unroll
    for (int ni = 0; ni < 4; ++ni)
      bfr[ni] = BFRAG(bf, (wn << 6) + (ni << 4) + la15, 0);
    if (more) ST_B(kt + 1, nb);
    __builtin_amdgcn_s_barrier();
    asm volatile("s_waitcnt lgkmcnt(0)" ::: "memory");
    MFMA_Q(0, 0);
    __builtin_amdgcn_s_barrier();

    // ---- P2: A q1 ks0 (B regs reused); stage A(kt+1) ----
#pragma unroll
    for (int mi = 0; mi < 4; ++mi)
      afr[mi] = AFRAG(bf, (wm << 7) + ((mi + 4) << 4) + la15, 0);
    if (more) ST_A(kt + 1, nb);
    __builtin_amdgcn_s_barrier();
    asm volatile("s_waitcnt lgkmcnt(0)" ::: "memory");
    MFMA_Q(4, 0);
    __builtin_amdgcn_s_barrier();

    // ---- P3: A q0 ks1 + B ks1 ----
#pragma unroll
    for (int mi = 0; mi < 4; ++mi)
      afr[mi] = AFRAG(bf, (wm << 7) + (mi << 4) + la15, 1);
#pragma unroll
    for (int ni = 0; ni < 4; ++ni)
      bfr[ni] = BFRAG(bf, (wn << 6) + (ni << 4) + la15, 1);
    __builtin_amdgcn_s_barrier();
    asm volatile("s_waitcnt lgkmcnt(0)" ::: "memory");
    MFMA_Q(0, 1);
    __builtin_amdgcn_s_barrier();

    // ---- P4: A q1 ks1; vmcnt(0) with ~2.5 phases of slack since P2 ----
#pragma unroll
    for (int mi = 0; mi < 4; ++mi)
      afr[mi] = AFRAG(bf, (wm << 7) + ((mi + 4) << 4) + la15, 1);
    __builtin_amdgcn_s_barrier();
    asm volatile("s_waitcnt lgkmcnt(0)" ::: "memory");
    MFMA_Q(4, 1);
    if (more) asm volatile("s_waitcnt vmcnt(0)" ::: "memory");
    __builtin_amdgcn_s_barrier();
  }

  // ---- epilogue: D row = o ((lane>>4)*4+reg), col = n (lane&15) ----
  const int lr = (lane >> 4) << 2;
#pragma unroll
  for (int ni = 0; ni < 4; ++ni) {
    const int ng = n0 + (wn << 6) + (ni << 4) + la15;
    const int b  = ng / 3136;
    const int s  = ng - b * 3136;
    float* op = out + (size_t)b * (O_DIM * 3136) + s;
#pragma unroll
    for (int mi = 0; mi < 8; ++mi) {
      const int og = (wm << 7) + (mi << 4) + lr;
#pragma unroll
      for (int r = 0; r < 4; ++r)
        op[(size_t)(og + r) * 3136] = acc[mi][ni][r] + 2.0f * bias[og + r];
    }
  }
}

// ---------------------------------------------------------------------------
extern "C" void kernel_launch(void* const* d_in, const int* in_sizes, int n_in,
                              void* d_out, int out_size, void* d_ws, size_t ws_size,
                              hipStream_t stream) {
  const float* x    = (const float*)d_in[0];
  const float* S1s  = (const float*)d_in[1];
  const float* U1s  = (const float*)d_in[2];
  const float* U2s  = (const float*)d_in[3];
  const float* S2s  = (const float*)d_in[4];
  const float* bias = (const float*)d_in[5];
  float* out = (float*)d_out;
  (void)ws_size;

  unsigned short* xt = (unsigned short*)d_ws;
  unsigned short* Wt = (unsigned short*)((char*)d_ws + (size_t)32 * XT_H * XT_ROW * 2);

  pad_kernel<<<dim3(32 * XT_H), dim3(256), 0, stream>>>(x, xt);
  wt_kernel<<<dim3(72), dim3(256), 0, stream>>>(S1s, U1s, U2s, S2s, Wt);
  gemm_kernel<<<dim3(392), dim3(512), 0, stream>>>(Wt, xt, bias, out);
}